// Round 1
// baseline (127.419 us; speedup 1.0000x reference)
//
#include <hip/hip_runtime.h>

#define NCC 64
#define NFF 16
#define NZ  80
#define BLK 128
// per-thread LDS slots: 0..62 cdf (later reused 0..79 as weight staging), 80..95 sorted fine
#define STRIDE 97

__device__ __forceinline__ float zc_of(int i) {
    // z = 2 + 4 * (i/63), matching jnp.linspace(0,1,64) scaled
    return fmaf(4.0f, (float)i * (1.0f / 63.0f), 2.0f);
}
__device__ __forceinline__ float tm_of(int i) {
    return 0.5f * (zc_of(i) + zc_of(i + 1));
}
__device__ __forceinline__ float fast_rcp(float x) { return __builtin_amdgcn_rcpf(x); }
__device__ __forceinline__ float sigmoidf(float x) { return fast_rcp(1.0f + __expf(-x)); }

__global__ void __launch_bounds__(BLK, 2)
VolumeRenderer_16192026706363_kernel(const float* __restrict__ ros,
                                     const float* __restrict__ rds,
                                     const float* __restrict__ w_sigma,
                                     const float* __restrict__ w_feat,
                                     const float* __restrict__ u,
                                     float* __restrict__ out,
                                     int nrays)
{
    __shared__ float lds[BLK * STRIDE];
    const int tid = threadIdx.x;
    const int n = blockIdx.x * BLK + tid;
    float* my = &lds[tid * STRIDE];

    // --- load ray + weights -------------------------------------------------
    const float ro0 = ros[n * 3 + 0], ro1 = ros[n * 3 + 1], ro2 = ros[n * 3 + 2];
    const float rd0 = rds[n * 3 + 0], rd1 = rds[n * 3 + 1], rd2 = rds[n * 3 + 2];
    const float s0 = w_sigma[0], s1 = w_sigma[1], s2 = w_sigma[2];
    float wf[9];
#pragma unroll
    for (int k = 0; k < 9; k++) wf[k] = w_feat[k];  // wf[c*3+k] = w_feat[c][k]

    // --- coarse pass: transmittance -> unnormalized cdf in LDS --------------
    float T = 1.0f, cum = 0.0f;
    float dist = zc_of(1) - zc_of(0);
    my[0] = 0.0f;  // cdf[0] = 0
    for (int i = 0; i < NCC; i++) {
        float z = zc_of(i);
        if (i < NCC - 1) dist = zc_of(i + 1) - z;  // last dist repeats
        float p0 = fmaf(rd0, z, ro0);
        float p1 = fmaf(rd1, z, ro1);
        float p2 = fmaf(rd2, z, ro2);
        float sg = p0 * s0 + p1 * s1 + p2 * s2;
        float e = __expf(-fmaxf(sg, 0.0f) * dist);
        float alpha = 1.0f - e;
        float w = alpha * T;
        T *= (1.0f - alpha + 1e-10f);
        if (i >= 1 && i <= 62) {
            cum += w + 1e-5f;     // weights[:,1:-1] + eps
            my[i] = cum;          // slot i = unnormalized cdf[i]
        }
    }
    const float invS = 1.0f / cum;
    for (int i = 1; i <= 62; i++) my[i] *= invS;   // normalize cdf in place

    // --- sample_pdf: 16 independent binary searches (ILP-friendly) ----------
    const float4* u4p = reinterpret_cast<const float4*>(u + (size_t)n * 16);
    float tv[16];
#pragma unroll
    for (int q = 0; q < 4; q++) {
        float4 uq = u4p[q];
#pragma unroll
        for (int r = 0; r < 4; r++) {
            float uu;
            if (r == 0) uu = uq.x; else if (r == 1) uu = uq.y;
            else if (r == 2) uu = uq.z; else uu = uq.w;
            // lower_bound over cdf[0..62], result in [0,63]
            int lo = 0, hi = 63;
#pragma unroll
            for (int s = 0; s < 6; s++) {
                int mid = (lo + hi) >> 1;
                bool lt = (my[mid] < uu);
                lo = lt ? mid + 1 : lo;
                hi = lt ? hi : mid;
            }
            int ind = lo;
            int below = (ind - 1 > 0) ? ind - 1 : 0;
            int above = (ind < 62) ? ind : 62;
            float c0 = my[below], c1 = my[above];
            float b0 = tm_of(below), b1 = tm_of(above);
            float denom = c1 - c0;
            denom = (denom < 1e-5f) ? 1.0f : denom;
            tv[q * 4 + r] = fmaf((uu - c0) / denom, (b1 - b0), b0);
        }
    }

    // --- bitonic sort of the 16 fine samples (registers, unstable = OK) -----
#pragma unroll
    for (int k = 2; k <= 16; k <<= 1) {
#pragma unroll
        for (int j = k >> 1; j > 0; j >>= 1) {
#pragma unroll
            for (int i = 0; i < 16; i++) {
                int l = i ^ j;
                if (l > i) {
                    float a = tv[i], b = tv[l];
                    float mn = fminf(a, b), mx = fmaxf(a, b);
                    bool up = ((i & k) == 0);
                    tv[i] = up ? mn : mx;
                    tv[l] = up ? mx : mn;
                }
            }
        }
    }
#pragma unroll
    for (int i = 0; i < 16; i++) my[80 + i] = tv[i];

    // --- merge coarse+fine, streaming volume integral -----------------------
    int ic = 0, jf = 0;
    float zch = 2.0f;        // zc_of(0)
    float zfh = my[80];
    float T2 = 1.0f, acc0 = 0.0f, acc1 = 0.0f, acc2 = 0.0f, accd = 0.0f;

    auto pop = [&]() -> float {
        float r;
        bool takeC = (zch <= zfh);   // exhausted side is +INF sentinel
        if (takeC) {
            r = zch; ic++;
            zch = (ic < NCC) ? zc_of(ic) : 3.0e38f;
        } else {
            r = zfh; jf++;
            zfh = (jf < NFF) ? my[80 + jf] : 3.0e38f;
        }
        return r;
    };

    auto process = [&](float z, float d, int slot) {
        float p0 = fmaf(rd0, z, ro0);
        float p1 = fmaf(rd1, z, ro1);
        float p2 = fmaf(rd2, z, ro2);
        float sg = p0 * s0 + p1 * s1 + p2 * s2;
        float e = __expf(-fmaxf(sg, 0.0f) * d);
        float alpha = 1.0f - e;
        float w = alpha * T2;
        T2 *= (1.0f - alpha + 1e-10f);
        my[slot] = w;  // stage weight (cdf area is dead)
        float f0 = sigmoidf(fmaf(p0, wf[0], fmaf(p1, wf[3], p2 * wf[6])));
        float f1 = sigmoidf(fmaf(p0, wf[1], fmaf(p1, wf[4], p2 * wf[7])));
        float f2 = sigmoidf(fmaf(p0, wf[2], fmaf(p1, wf[5], p2 * wf[8])));
        acc0 = fmaf(w, f0, acc0);
        acc1 = fmaf(w, f1, acc1);
        acc2 = fmaf(w, f2, acc2);
        accd = fmaf(w, z, accd);
    };

    float zprev = pop();
    float dlast = 0.0f;
    for (int i = 1; i < NZ; i++) {
        float z = pop();
        float d = z - zprev;
        process(zprev, d, i - 1);
        zprev = z; dlast = d;
    }
    process(zprev, dlast, NZ - 1);   // last sample uses repeated dist

    // --- rgb + depth --------------------------------------------------------
    out[(size_t)n * 3 + 0] = acc0;
    out[(size_t)n * 3 + 1] = acc1;
    out[(size_t)n * 3 + 2] = acc2;
    out[(size_t)nrays * 3 + n] = accd;

    // --- coalesced block write of staged weights ----------------------------
    __syncthreads();
    const size_t wbase = (size_t)nrays * 4 + (size_t)blockIdx.x * BLK * NZ;
    for (int k = tid; k < BLK * NZ; k += BLK) {
        int t = k / NZ;
        int i = k - t * NZ;
        out[wbase + k] = lds[t * STRIDE + i];
    }
}

extern "C" void kernel_launch(void* const* d_in, const int* in_sizes, int n_in,
                              void* d_out, int out_size, void* d_ws, size_t ws_size,
                              hipStream_t stream) {
    const float* ros = (const float*)d_in[0];
    const float* rds = (const float*)d_in[1];
    const float* w_sigma = (const float*)d_in[2];
    const float* w_feat = (const float*)d_in[3];
    const float* u = (const float*)d_in[4];
    float* out = (float*)d_out;

    int nrays = in_sizes[0] / 3;          // 131072
    int grid = nrays / BLK;               // 1024
    VolumeRenderer_16192026706363_kernel<<<grid, BLK, 0, stream>>>(
        ros, rds, w_sigma, w_feat, u, out, nrays);
}

// Round 2
// 107.566 us; speedup vs baseline: 1.1846x; 1.1846x over previous
//
#include <hip/hip_runtime.h>

#define NCC 64
#define NFF 16
#define NZ  80
#define BLK 128
// per-thread LDS: slots 0..62 hold unnormalized CDF during searches,
// then slots 0..15 are reused for the sorted fine z's. stride 63 (odd mult
// of 4B => bank (k - lane) % 32 for uniform k => 2 lanes/bank = free).
#define SLOTS 63

__device__ __forceinline__ float zc_of(int i) {
    return fmaf(4.0f, (float)i * (1.0f / 63.0f), 2.0f);   // linspace(2,6,64)
}
__device__ __forceinline__ float tm_of(int i) {
    return 0.5f * (zc_of(i) + zc_of(i + 1));
}
__device__ __forceinline__ float fast_rcp(float x) { return __builtin_amdgcn_rcpf(x); }

__global__ void __launch_bounds__(BLK, 2)
VolumeRenderer_16192026706363_kernel(const float* __restrict__ ros,
                                     const float* __restrict__ rds,
                                     const float* __restrict__ w_sigma,
                                     const float* __restrict__ w_feat,
                                     const float* __restrict__ u,
                                     float* __restrict__ out,
                                     int nrays)
{
    __shared__ float lds[BLK * SLOTS];
    const int tid = threadIdx.x;
    const int n = blockIdx.x * BLK + tid;
    float* my = &lds[tid * SLOTS];

    // --- issue u loads early (independent of everything below) -------------
    const float4* u4p = reinterpret_cast<const float4*>(u + (size_t)n * 16);
    float4 uq0 = u4p[0], uq1 = u4p[1], uq2 = u4p[2], uq3 = u4p[3];

    // --- ray + affine field coefficients ------------------------------------
    const float ro0 = ros[n * 3 + 0], ro1 = ros[n * 3 + 1], ro2 = ros[n * 3 + 2];
    const float rd0 = rds[n * 3 + 0], rd1 = rds[n * 3 + 1], rd2 = rds[n * 3 + 2];
    const float s0 = w_sigma[0], s1 = w_sigma[1], s2 = w_sigma[2];
    // sigma(z) = sgA + sgB*z ; logit_c(z) = fA[c] + fB[c]*z
    const float sgA = ro0 * s0 + ro1 * s1 + ro2 * s2;
    const float sgB = rd0 * s0 + rd1 * s1 + rd2 * s2;
    float fA[3], fB[3];
#pragma unroll
    for (int c = 0; c < 3; c++) {
        fA[c] = ro0 * w_feat[0 * 3 + c] + ro1 * w_feat[1 * 3 + c] + ro2 * w_feat[2 * 3 + c];
        fB[c] = rd0 * w_feat[0 * 3 + c] + rd1 * w_feat[1 * 3 + c] + rd2 * w_feat[2 * 3 + c];
    }

    const float LOG2E = 1.4426950408889634f;
    const float DIST  = 4.0f / 63.0f;          // constant coarse spacing (last repeats)
    const float K1    = -DIST * LOG2E;         // e = exp2(relu(sg)*K1)

    // --- coarse pass: unnormalized cdf in my[1..62] -------------------------
    float T = 1.0f, cum = 0.0f;
    my[0] = 0.0f;
    {   // i = 0 peeled (weight not part of cdf, but T advances)
        float e = exp2f(fmaxf(sgA + sgB * 2.0f, 0.0f) * K1);
        T = e + 1e-10f;
    }
    for (int i = 1; i <= 62; i++) {
        float sg = fmaf(sgB, zc_of(i), sgA);
        float e = exp2f(fmaxf(sg, 0.0f) * K1);
        float w = (1.0f - e) * T;
        cum += w + 1e-5f;
        my[i] = cum;
        T *= (e + 1e-10f);
    }
    const float S = cum;
    const float invS = 1.0f / S;

    // --- sample_pdf: 16 independent binary searches on UNNORMALIZED cdf -----
    float tv[16];
#pragma unroll
    for (int q = 0; q < 16; q++) {
        float uu;
        {
            float4 uq = (q < 4) ? uq0 : (q < 8) ? uq1 : (q < 12) ? uq2 : uq3;
            int r = q & 3;
            uu = (r == 0) ? uq.x : (r == 1) ? uq.y : (r == 2) ? uq.z : uq.w;
        }
        float us = uu * S;                     // search threshold in unnormalized space
        int lo = 0, hi = 63;
#pragma unroll
        for (int s = 0; s < 6; s++) {
            int mid = (lo + hi) >> 1;
            bool lt = (my[mid] < us);
            lo = lt ? mid + 1 : lo;
            hi = lt ? hi : mid;
        }
        int ind = lo;
        int below = (ind - 1 > 0) ? ind - 1 : 0;
        int above = (ind < 62) ? ind : 62;
        float c0 = my[below] * invS, c1 = my[above] * invS;
        float b0 = tm_of(below);
        float denom = c1 - c0;
        denom = (denom < 1e-5f) ? 1.0f : denom;
        float db = (4.0f / 63.0f) * (float)(above - below);   // tm is linear in idx
        tv[q] = fmaf((uu - c0) / denom, db, b0);
    }

    // --- bitonic sort of 16 fine samples (registers) ------------------------
#pragma unroll
    for (int k = 2; k <= 16; k <<= 1) {
#pragma unroll
        for (int j = k >> 1; j > 0; j >>= 1) {
#pragma unroll
            for (int i = 0; i < 16; i++) {
                int l = i ^ j;
                if (l > i) {
                    float a = tv[i], b = tv[l];
                    float mn = fminf(a, b), mx = fmaxf(a, b);
                    bool up = ((i & k) == 0);
                    tv[i] = up ? mn : mx;
                    tv[l] = up ? mx : mn;
                }
            }
        }
    }
    // cdf is dead; reuse my[0..15] for sorted fine z's
#pragma unroll
    for (int i = 0; i < 16; i++) my[i] = tv[i];

    // --- merge + streaming volume integral, weights written as float4 -------
    int ic = 0, jf = 0;
    float zch = 2.0f;
    float zfh = my[0];
    float T2 = 1.0f, acc0 = 0.0f, acc1 = 0.0f, acc2 = 0.0f, accd = 0.0f;

    auto pop = [&]() -> float {
        bool takeC = (zch <= zfh);            // coarse wins ties (stable argsort)
        float r = takeC ? zch : zfh;
        if (takeC) { ic++; zch = (ic < NCC) ? zc_of(ic) : 3.0e38f; }
        else       { jf++; zfh = (jf < NFF) ? my[jf] : 3.0e38f; }
        return r;
    };

    auto proc = [&](float z, float d) -> float {
        float sg = fmaf(sgB, z, sgA);
        float e = exp2f(fmaxf(sg, 0.0f) * d * (-LOG2E));
        float alpha = 1.0f - e;
        float w = alpha * T2;
        T2 *= (e + 1e-10f);
        float f0 = fast_rcp(1.0f + exp2f(fmaf(fB[0], z, fA[0]) * (-LOG2E)));
        float f1 = fast_rcp(1.0f + exp2f(fmaf(fB[1], z, fA[1]) * (-LOG2E)));
        float f2 = fast_rcp(1.0f + exp2f(fmaf(fB[2], z, fA[2]) * (-LOG2E)));
        acc0 = fmaf(w, f0, acc0);
        acc1 = fmaf(w, f1, acc1);
        acc2 = fmaf(w, f2, acc2);
        accd = fmaf(w, z, accd);
        return w;
    };

    float* wptr = out + (size_t)nrays * 4 + (size_t)n * NZ;   // 16B aligned (80*4)
    float zprev = pop();
    float dlast = 0.0f;
    float wq[4];

    for (int g = 0; g < 19; g++) {            // samples 0..75
#pragma unroll
        for (int j = 0; j < 4; j++) {
            float z = pop();
            wq[j] = proc(zprev, z - zprev);
            zprev = z;
        }
        *reinterpret_cast<float4*>(wptr + g * 4) =
            make_float4(wq[0], wq[1], wq[2], wq[3]);
    }
    // last group: samples 76,77,78 normal; sample 79 repeats last dist
#pragma unroll
    for (int j = 0; j < 3; j++) {
        float z = pop();
        dlast = z - zprev;
        wq[j] = proc(zprev, dlast);
        zprev = z;
    }
    wq[3] = proc(zprev, dlast);
    *reinterpret_cast<float4*>(wptr + 19 * 4) =
        make_float4(wq[0], wq[1], wq[2], wq[3]);

    // --- rgb + depth --------------------------------------------------------
    out[(size_t)n * 3 + 0] = acc0;
    out[(size_t)n * 3 + 1] = acc1;
    out[(size_t)n * 3 + 2] = acc2;
    out[(size_t)nrays * 3 + n] = accd;
}

extern "C" void kernel_launch(void* const* d_in, const int* in_sizes, int n_in,
                              void* d_out, int out_size, void* d_ws, size_t ws_size,
                              hipStream_t stream) {
    const float* ros = (const float*)d_in[0];
    const float* rds = (const float*)d_in[1];
    const float* w_sigma = (const float*)d_in[2];
    const float* w_feat = (const float*)d_in[3];
    const float* u = (const float*)d_in[4];
    float* out = (float*)d_out;

    int nrays = in_sizes[0] / 3;          // 131072
    int grid = nrays / BLK;               // 1024
    VolumeRenderer_16192026706363_kernel<<<grid, BLK, 0, stream>>>(
        ros, rds, w_sigma, w_feat, u, out, nrays);
}